// Round 12
// baseline (112.347 us; speedup 1.0000x reference)
//
#include <hip/hip_runtime.h>
#include <hip/hip_bf16.h>

typedef __hip_bfloat16 bf16;
typedef float    f32x16 __attribute__((ext_vector_type(16)));
typedef __bf16   bf16x8 __attribute__((ext_vector_type(8)));
typedef unsigned uint4v __attribute__((ext_vector_type(4)));
typedef int      i32x2  __attribute__((ext_vector_type(2)));

#define N_TOK 4096
#define SCALE_L2E 0.2550348952703927f  // 32^-0.5 * log2(e), folded into q weights

__device__ __forceinline__ bf16x8 ld8(const bf16* p) { return *(const bf16x8*)p; }
__device__ __forceinline__ unsigned pack2(float a, float b) {
    unsigned short ua = __builtin_bit_cast(unsigned short, (__bf16)a);
    unsigned short ub = __builtin_bit_cast(unsigned short, (__bf16)b);
    return (unsigned)ua | ((unsigned)ub << 16);
}
__device__ __forceinline__ unsigned short f2b(float f) {
    return __builtin_bit_cast(unsigned short, (__bf16)f);
}
__device__ __forceinline__ __bf16 us2bf(unsigned short u) {
    return __builtin_bit_cast(__bf16, u);
}

// ---------------------------------------------------------------------------
// Kernel 0: convert weights to bf16 (q rows pre-scaled). 65536 elems exactly.
// grid 256, block 256.
// ---------------------------------------------------------------------------
__global__ void wconv(const float* __restrict__ wqkv, const float* __restrict__ wout,
                      bf16* __restrict__ wq, bf16* __restrict__ wo) {
    int idx = blockIdx.x * 256 + threadIdx.x;
    if (idx < 384 * 128) {
        float sc = (idx < 128 * 128) ? SCALE_L2E : 1.0f;
        ((unsigned short*)wq)[idx] = f2b(wqkv[idx] * sc);
    } else {
        int j = idx - 384 * 128;
        ((unsigned short*)wo)[j] = f2b(wout[j]);
    }
}

// ---------------------------------------------------------------------------
// Kernel A: qkv projection via MFMA. 64-token X tile in LDS; W fragments in
// REGISTERS from pre-converted bf16 (no per-block W restaging).
// Wave (tc, oh) computes o-tile (z*2+oh) for tokens tc*32.. : ot 0-3 = q heads,
// 4-7 = k heads (D[tok][d] via mfma(X,W)), 8-11 = v heads (D[d][tok]).
// grid (64, 2, 6), block 256.
// ---------------------------------------------------------------------------
__global__ void __launch_bounds__(256)
qkv_mfma(const float* __restrict__ x, const bf16* __restrict__ wq,
         bf16* __restrict__ qt, bf16* __restrict__ kt, bf16* __restrict__ vt) {
    int tok0 = blockIdx.x * 64;
    int b    = blockIdx.y;
    int z    = blockIdx.z;
    __shared__ unsigned short xs[128 * 64];
    {   // stage X tile: thread t -> row c = t>>1, 32-token half
        int c = threadIdx.x >> 1, half = threadIdx.x & 1;
        const float4* x4 = (const float4*)(x + (size_t)(b * 128 + c) * N_TOK + tok0 + half * 32);
        unsigned* dst = (unsigned*)&xs[c * 64 + half * 32];
#pragma unroll
        for (int k = 0; k < 8; ++k) {
            float4 v4 = x4[k];
            dst[2 * k]     = pack2(v4.x, v4.y);
            dst[2 * k + 1] = pack2(v4.z, v4.w);
        }
    }
    __syncthreads();
    int lane = threadIdx.x & 63, wv = threadIdx.x >> 6;
    int tc = wv & 1, oh = wv >> 1;
    int ot = z * 2 + oh;                 // 0..11
    int o0 = ot * 32;
    int i = lane & 31, hl = lane >> 5;

    bf16x8 xf[8], wf[8];
#pragma unroll
    for (int kb = 0; kb < 8; ++kb) {
        bf16x8 f;
#pragma unroll
        for (int e = 0; e < 8; ++e) f[e] = us2bf(xs[(kb * 16 + hl * 8 + e) * 64 + tc * 32 + i]);
        xf[kb] = f;
        wf[kb] = ld8(wq + (size_t)(o0 + i) * 128 + kb * 16 + hl * 8);
    }

    f32x16 D;
#pragma unroll
    for (int r = 0; r < 16; ++r) D[r] = 0.f;

    if (ot < 8) {  // q or k: D[tok][d]
#pragma unroll
        for (int kb = 0; kb < 8; ++kb)
            D = __builtin_amdgcn_mfma_f32_32x32x16_bf16(xf[kb], wf[kb], D, 0, 0, 0);
        bf16* base = (ot < 4) ? qt : kt;
        int h = ot & 3;
        unsigned short* dst = (unsigned short*)(base +
            ((size_t)(b * 4 + h) * N_TOK + tok0 + tc * 32) * 32);
#pragma unroll
        for (int r = 0; r < 16; ++r) {
            int tr = (r & 3) + 8 * (r >> 2) + 4 * hl;
            dst[tr * 32 + i] = f2b(D[r]);
        }
    } else {       // v: D[d][tok]
#pragma unroll
        for (int kb = 0; kb < 8; ++kb)
            D = __builtin_amdgcn_mfma_f32_32x32x16_bf16(wf[kb], xf[kb], D, 0, 0, 0);
        int h = ot - 8;
        unsigned short* dst = (unsigned short*)(vt +
            (size_t)(b * 4 + h) * (32 * N_TOK) + tok0 + tc * 32);
#pragma unroll
        for (int r = 0; r < 16; ++r) {
            int dr = (r & 3) + 8 * (r >> 2) + 4 * hl;
            dst[(size_t)dr * N_TOK + i] = f2b(D[r]);
        }
    }
}

// ---------------------------------------------------------------------------
// Kernel B: MFMA flash attention. Block 512 thr = 8 waves = 2 qpairs x 4
// key-quarters; wave = 64 queries (2 qtiles, 2 interleaved dep-chains) x
// 1024 keys (quarter of each 128-key chunk). K LDS rows padded to 40 elems
// (16B-aligned, ~4-way banks max); V rows XOR-swizzled ((d&7)<<4, m214).
// 32 chunks, double-buffered, loads issued before compute, 1 barrier/chunk.
// grid 256 (bh = bid&7 -> XCD-locked), block 512.
// ---------------------------------------------------------------------------
#define KROW 40
#define KBUF_SZ (128 * KROW * 2)          // 10240 B
#define VBUF_OFF (2 * KBUF_SZ)            // 20480
#define VBUF_SZ (32 * 128 * 2)            // 8192 B

__global__ void __launch_bounds__(512)
attn_mfma(const bf16* __restrict__ qt, const bf16* __restrict__ kt,
          const bf16* __restrict__ vt, bf16* __restrict__ ao) {
    int bid = blockIdx.x;
    int bh  = bid & 7;
    int qg  = bid >> 3;
    int tid = threadIdx.x;
    int lane = tid & 63, wv = tid >> 6;
    int qp = wv >> 2;                     // 0/1: query group of 64
    int ks = wv & 3;                      // key quarter within chunk
    int i = lane & 31, hl = lane >> 5;

    __shared__ char lds[2 * KBUF_SZ + 2 * VBUF_SZ];   // 36864 B

    const bf16* qb = qt + (size_t)bh * (N_TOK * 32) + (size_t)(qg * 128 + qp * 64) * 32;
    bf16x8 q1a = ld8(qb + i * 32 + hl * 8);
    bf16x8 q2a = ld8(qb + i * 32 + 16 + hl * 8);
    bf16x8 q1b = ld8(qb + (32 + i) * 32 + hl * 8);
    bf16x8 q2b = ld8(qb + (32 + i) * 32 + 16 + hl * 8);

    // staging addresses (per chunk of 128 keys)
    int u = tid;
    const bf16* ksrc = kt + (size_t)bh * (N_TOK * 32) + (u >> 2) * 32 + (u & 3) * 8;
    const bf16* vsrc = vt + (size_t)bh * (32 * N_TOK) + (size_t)(u >> 4) * N_TOK + (u & 15) * 8;
    int kdst = (u >> 2) * 80 + (u & 3) * 16;                              // bytes in K region
    int vdst = VBUF_OFF + (((u >> 4) * 256 + (u & 15) * 16) ^ (((u >> 4) & 7) << 4));

    // fragment read offsets (bytes)
    int koff1 = (ks * 32 + i) * 80 + hl * 16;
    int koff2 = koff1 + 32;
    int voff1 = VBUF_OFF + ((i * 256 + ks * 64 + hl * 16) ^ ((i & 7) << 4));
    int voff2 = VBUF_OFF + ((i * 256 + ks * 64 + 32 + hl * 16) ^ ((i & 7) << 4));

    f32x16 OA, OB, Z;
#pragma unroll
    for (int r = 0; r < 16; ++r) { OA[r] = 0.f; OB[r] = 0.f; Z[r] = 0.f; }
    float lA = 0.f, lB = 0.f;

    // prologue: stage chunk 0 into buf 0
    *(uint4v*)(lds + kdst) = *(const uint4v*)ksrc;
    *(uint4v*)(lds + vdst) = *(const uint4v*)vsrc;
    __syncthreads();

    for (int t = 0; t < 32; ++t) {
        int cur = t & 1;
        uint4v nk, nv;
        if (t < 31) {   // issue next chunk's loads early
            nk = *(const uint4v*)(ksrc + (size_t)(t + 1) * 128 * 32);
            nv = *(const uint4v*)(vsrc + (t + 1) * 128);
        }
        bf16x8 ka1 = __builtin_bit_cast(bf16x8, *(const uint4v*)(lds + cur * KBUF_SZ + koff1));
        bf16x8 ka2 = __builtin_bit_cast(bf16x8, *(const uint4v*)(lds + cur * KBUF_SZ + koff2));
        bf16x8 va1 = __builtin_bit_cast(bf16x8, *(const uint4v*)(lds + cur * VBUF_SZ + voff1));
        bf16x8 va2 = __builtin_bit_cast(bf16x8, *(const uint4v*)(lds + cur * VBUF_SZ + voff2));

        f32x16 SA = __builtin_amdgcn_mfma_f32_32x32x16_bf16(ka1, q1a, Z, 0, 0, 0);
        SA = __builtin_amdgcn_mfma_f32_32x32x16_bf16(ka2, q2a, SA, 0, 0, 0);
        f32x16 SB = __builtin_amdgcn_mfma_f32_32x32x16_bf16(ka1, q1b, Z, 0, 0, 0);
        SB = __builtin_amdgcn_mfma_f32_32x32x16_bf16(ka2, q2b, SB, 0, 0, 0);

        float pA[16], pB[16];
#pragma unroll
        for (int r = 0; r < 16; ++r) { pA[r] = __builtin_amdgcn_exp2f(SA[r]); }
#pragma unroll
        for (int r = 0; r < 16; ++r) { pB[r] = __builtin_amdgcn_exp2f(SB[r]); }
#pragma unroll
        for (int r = 0; r < 16; ++r) { lA += pA[r]; lB += pB[r]; }

        {
            unsigned k0 = pack2(pA[0], pA[1]),   k1 = pack2(pA[2], pA[3]);
            unsigned k2 = pack2(pA[4], pA[5]),   k3 = pack2(pA[6], pA[7]);
            unsigned k4 = pack2(pA[8], pA[9]),   k5 = pack2(pA[10], pA[11]);
            unsigned k6 = pack2(pA[12], pA[13]), k7 = pack2(pA[14], pA[15]);
            i32x2 t1 = __builtin_amdgcn_permlane32_swap((int)k0, (int)k2, false, false);
            i32x2 t2 = __builtin_amdgcn_permlane32_swap((int)k1, (int)k3, false, false);
            i32x2 t3 = __builtin_amdgcn_permlane32_swap((int)k4, (int)k6, false, false);
            i32x2 t4 = __builtin_amdgcn_permlane32_swap((int)k5, (int)k7, false, false);
            uint4v B1u = {(unsigned)t1.x, (unsigned)t2.x, (unsigned)t1.y, (unsigned)t2.y};
            uint4v B2u = {(unsigned)t3.x, (unsigned)t4.x, (unsigned)t3.y, (unsigned)t4.y};
            OA = __builtin_amdgcn_mfma_f32_32x32x16_bf16(va1, __builtin_bit_cast(bf16x8, B1u), OA, 0, 0, 0);
            OA = __builtin_amdgcn_mfma_f32_32x32x16_bf16(va2, __builtin_bit_cast(bf16x8, B2u), OA, 0, 0, 0);
        }
        {
            unsigned k0 = pack2(pB[0], pB[1]),   k1 = pack2(pB[2], pB[3]);
            unsigned k2 = pack2(pB[4], pB[5]),   k3 = pack2(pB[6], pB[7]);
            unsigned k4 = pack2(pB[8], pB[9]),   k5 = pack2(pB[10], pB[11]);
            unsigned k6 = pack2(pB[12], pB[13]), k7 = pack2(pB[14], pB[15]);
            i32x2 t1 = __builtin_amdgcn_permlane32_swap((int)k0, (int)k2, false, false);
            i32x2 t2 = __builtin_amdgcn_permlane32_swap((int)k1, (int)k3, false, false);
            i32x2 t3 = __builtin_amdgcn_permlane32_swap((int)k4, (int)k6, false, false);
            i32x2 t4 = __builtin_amdgcn_permlane32_swap((int)k5, (int)k7, false, false);
            uint4v B1u = {(unsigned)t1.x, (unsigned)t2.x, (unsigned)t1.y, (unsigned)t2.y};
            uint4v B2u = {(unsigned)t3.x, (unsigned)t4.x, (unsigned)t3.y, (unsigned)t4.y};
            OB = __builtin_amdgcn_mfma_f32_32x32x16_bf16(va1, __builtin_bit_cast(bf16x8, B1u), OB, 0, 0, 0);
            OB = __builtin_amdgcn_mfma_f32_32x32x16_bf16(va2, __builtin_bit_cast(bf16x8, B2u), OB, 0, 0, 0);
        }

        if (t < 31) {   // publish next chunk
            int nxt = cur ^ 1;
            *(uint4v*)(lds + nxt * KBUF_SZ + kdst) = nk;
            *(uint4v*)(lds + nxt * VBUF_SZ + vdst) = nv;
        }
        __syncthreads();
    }

    // ---- combine 4 key-quarter partials per qp, one qtile phase at a time ----
    lA += __shfl_xor(lA, 32);
    lB += __shfl_xor(lB, 32);
    float* fb = (float*)lds;                       // [qp2][ks3][16][64] = 24576 B
    float* ls = (float*)(lds + 24576);             // [qp2][ks3][64]
    unsigned short* aop = (unsigned short*)(ao + (size_t)bh * (32 * N_TOK) + qg * 128 + qp * 64);

#pragma unroll
    for (int qtl = 0; qtl < 2; ++qtl) {
        const f32x16& O = qtl ? OB : OA;
        float l = qtl ? lB : lA;
        if (ks) {
            int s = qp * 3 + ks - 1;
#pragma unroll
            for (int r = 0; r < 16; ++r) fb[(s * 16 + r) * 64 + lane] = O[r];
            ls[s * 64 + lane] = l;
        }
        __syncthreads();
        if (ks == 0) {
            int s0 = qp * 3;
            float lt = l + ls[s0 * 64 + lane] + ls[(s0 + 1) * 64 + lane] + ls[(s0 + 2) * 64 + lane];
            float inv = 1.f / lt;
#pragma unroll
            for (int r = 0; r < 16; ++r) {
                float sv = O[r] + fb[((s0) * 16 + r) * 64 + lane] +
                           fb[((s0 + 1) * 16 + r) * 64 + lane] +
                           fb[((s0 + 2) * 16 + r) * 64 + lane];
                int d = (r & 3) + 8 * (r >> 2) + 4 * hl;
                aop[(size_t)d * N_TOK + qtl * 32 + i] = f2b(sv * inv);
            }
        }
        __syncthreads();
    }
}

// ---------------------------------------------------------------------------
// Kernel C: out projection via MFMA + bias + residual; W in registers.
// grid (64, 2, 2), block 256. Wave (tc, oh): o-tile z*2+oh.
// ---------------------------------------------------------------------------
__global__ void __launch_bounds__(256)
out_mfma(const bf16* __restrict__ ao, const bf16* __restrict__ wo,
         const float* __restrict__ bias, const float* __restrict__ x,
         float* __restrict__ out) {
    int tok0 = blockIdx.x * 64;
    int b    = blockIdx.y;
    int z    = blockIdx.z;
    __shared__ unsigned short as_[128 * 64];
    {   // stage ao tile (bf16): thread t -> row c, 32-token half
        int c = threadIdx.x >> 1, half = threadIdx.x & 1;
        const uint4v* src = (const uint4v*)(ao + (size_t)(b * 128 + c) * N_TOK + tok0 + half * 32);
        uint4v* dst = (uint4v*)&as_[c * 64 + half * 32];
#pragma unroll
        for (int k = 0; k < 4; ++k) dst[k] = src[k];
    }
    __syncthreads();
    int lane = threadIdx.x & 63, wv = threadIdx.x >> 6;
    int tc = wv & 1, oh = wv >> 1;
    int o0 = (z * 2 + oh) * 32;
    int i = lane & 31, hl = lane >> 5;

    bf16x8 af[8], wf[8];
#pragma unroll
    for (int kb = 0; kb < 8; ++kb) {
        bf16x8 f;
#pragma unroll
        for (int e = 0; e < 8; ++e) f[e] = us2bf(as_[(kb * 16 + hl * 8 + e) * 64 + tc * 32 + i]);
        af[kb] = f;
        wf[kb] = ld8(wo + (size_t)(o0 + i) * 128 + kb * 16 + hl * 8);
    }

    f32x16 D;
#pragma unroll
    for (int r = 0; r < 16; ++r) D[r] = 0.f;
#pragma unroll
    for (int kb = 0; kb < 8; ++kb)
        D = __builtin_amdgcn_mfma_f32_32x32x16_bf16(wf[kb], af[kb], D, 0, 0, 0);

#pragma unroll
    for (int r = 0; r < 16; ++r) {
        int o_r = o0 + (r & 3) + 8 * (r >> 2) + 4 * hl;
        size_t idx = ((size_t)b * 128 + o_r) * N_TOK + tok0 + tc * 32 + i;
        out[idx] = D[r] + bias[o_r] + x[idx];
    }
}

// ---------------------------------------------------------------------------
extern "C" void kernel_launch(void* const* d_in, const int* in_sizes, int n_in,
                              void* d_out, int out_size, void* d_ws, size_t ws_size,
                              hipStream_t stream) {
    const float* x     = (const float*)d_in[0];
    const float* w_qkv = (const float*)d_in[1];
    const float* w_out = (const float*)d_in[2];
    const float* b_out = (const float*)d_in[3];
    float* out = (float*)d_out;

    bf16* qt = (bf16*)d_ws;                          // [8][4096][32] bf16 = 2 MB
    bf16* kt = qt + (size_t)8 * N_TOK * 32;          // [8][4096][32] bf16 = 2 MB
    bf16* vt = kt + (size_t)8 * N_TOK * 32;          // [8][32][4096] bf16 = 2 MB
    bf16* ao = vt + (size_t)8 * N_TOK * 32;          // [2][128][4096] bf16 = 2 MB
    bf16* wq = ao + (size_t)2 * 128 * N_TOK;         // [384][128] bf16
    bf16* wo = wq + (size_t)384 * 128;               // [128][128] bf16

    wconv    <<<dim3(256), 256, 0, stream>>>(w_qkv, w_out, wq, wo);
    qkv_mfma <<<dim3(64, 2, 6), 256, 0, stream>>>(x, wq, qt, kt, vt);
    attn_mfma<<<dim3(256), 512, 0, stream>>>(qt, kt, vt, ao);
    out_mfma <<<dim3(64, 2, 2), 256, 0, stream>>>(ao, wo, b_out, x, out);
}